// Round 9
// baseline (3268.885 us; speedup 1.0000x reference)
//
#include <hip/hip_runtime.h>

static constexpr int T_STEPS = 512;
static constexpr int BATCH   = 64;
static constexpr int DIN     = 256;
static constexpr int HID     = 512;
static constexpr int KDIM    = DIN + HID;   // 768
static constexpr int S4      = 193;         // LDS row stride in float4 (192 data + 1 pad)
static constexpr int NBLK    = 256;
static constexpr int NPROD   = 64;          // producers (kslices) per bgroup

__device__ __forceinline__ float fast_sigmoid(float v) {
    return 1.0f / (1.0f + __expf(-v));
}
__device__ __forceinline__ float fast_tanh(float v) {
    return 1.0f - 2.0f / (__expf(2.0f * v) + 1.0f);
}

// Relaxed agent-scope ops: L1+L2 bypass, served at the device coherence
// point. No buffer_wbl2 / buffer_inv anywhere (rounds 1-3 lesson: per-WG
// full-L2 writeback+invalidate is catastrophic).
__device__ __forceinline__ void store_bypass(float* p, float v) {
    __hip_atomic_store((unsigned int*)p, __float_as_uint(v),
                       __ATOMIC_RELAXED, __HIP_MEMORY_SCOPE_AGENT);
}
__device__ __forceinline__ float load_bypass(const float* p) {
    return __uint_as_float(__hip_atomic_load((const unsigned int*)p,
                           __ATOMIC_RELAXED, __HIP_MEMORY_SCOPE_AGENT));
}
__device__ __forceinline__ void store_flag(unsigned* p, unsigned v) {
    __hip_atomic_store(p, v, __ATOMIC_RELAXED, __HIP_MEMORY_SCOPE_AGENT);
}
__device__ __forceinline__ unsigned load_flag(const unsigned* p) {
    return __hip_atomic_load(p, __ATOMIC_RELAXED, __HIP_MEMORY_SCOPE_AGENT);
}

// DPP-rotate add: v += lane_permuted(v). All-VALU (no LDS pipe). ctrl is a
// literal: 0xB1 quad_perm xor1, 0x4E quad_perm xor2, 0x124 row_ror:4,
// 0x128 row_ror:8 -> every lane holds its 16-lane row sum. 0x142
// row_bcast15: lanes 16-31 += lane15, 48-63 += lane47 -> lanes 16-31 hold
// sum(0..31), 48-63 hold sum(32..63). 0x143 row_bcast31: lanes 32-63 +=
// lane31 (= sum 0..31) -> lanes 48-63 hold the full 64-lane sum.
// bound_ctrl=1 zero-fills non-receiving lanes (harmless).
#define DPP_ADD(v, ctrl)                                                  \
    (v) += __uint_as_float(__builtin_amdgcn_update_dpp(                   \
        0u, __float_as_uint(v), (ctrl), 0xF, 0xF, true))

// ROUND 7:  per-producer flags + wave-wide __all poll; x-GEMM above wait.
// ROUND 8-11 (dead end): W-in-registers spills (128-VGPR allocator pin);
//           spill reload on the critical path ~doubles step time
//           (WRITE_SIZE 135->295MB signature). Design INSIDE 128 VGPRs.
// ROUND 12: E-reduce LDS ds_swizzle -> VALU DPP: 3555 -> 2766us.
// ROUND 13: retile 4x4/KQ16 -> 8x4/KQ32: conflicts 2.08e8 -> 2.1e6 (the
//           wv 4-way aliasing eliminated) but dur only -4%: conflict
//           cycles were a minor term; LDS READ INSTRUCTION COUNT
//           (72/thread x 12cyc) is the binding resource.
// ROUND 14: retile 8x4/KQ32 -> 8x8/KQ64: reads/thread = 192/KQ x (tb+tr)
//           = 72 -> 48 (-33% critical-path LDS). acc 64 f32 => schedule
//           the inner loop to fit 128 VGPRs: cv[8] resident, wv loaded in
//           PAIRS with sched_barrier(0) after each pair-group so the
//           compiler cannot cluster all 8 wv loads (peak live ~ acc64 +
//           cv32 + wv8 + addr ~ 110). Reduction gains row_bcast31 stage;
//           writer = lane 48/wave packs 16 f4 writes. x-part = exactly
//           K-stripe it=0 (f4 0..63), still hidden under the flag wait.
__global__ __launch_bounds__(512, 1)
void lstm_persistent(const float* __restrict__ x,
                     const float* __restrict__ Wf, const float* __restrict__ bfp,
                     const float* __restrict__ Wi, const float* __restrict__ bip,
                     const float* __restrict__ Wg, const float* __restrict__ bgp,
                     const float* __restrict__ Wo, const float* __restrict__ bop,
                     float* __restrict__ out, unsigned* __restrict__ flag_ws) {
    __shared__ float4 W4[32 * S4];        // 32 rows x 768 fp32
    __shared__ float4 C4[16 * S4];        // combined [x|h] for 16 b
    __shared__ float4 gates4[16 * 9];     // gates [16 b][36 f stride]
    __shared__ float  bias_s[32];

    const int tid = threadIdx.x;
    const int wg  = blockIdx.x;
    const int bgroup = (wg & 7) >> 1;                  // 0..3
    const int kslice = ((wg >> 3) << 1) | (wg & 1);    // 0..63
    const int bg0 = bgroup * 16;
    const int k0  = kslice * 8;

    // 64 flags per bgroup, packed 256 B (one wave-instruction covers all 64)
    unsigned* const flags = flag_ws + bgroup * NPROD;

    // ---- one-time: stage 32 weight rows (gate*8 + unit) into LDS ----
    {
        const int r    = tid >> 4;     // 0..31
        const int c0   = tid & 15;
        const int gate = r >> 3;
        const int unit = k0 + (r & 7);
        const float* wsrc = (gate == 0) ? Wf : (gate == 1) ? Wi : (gate == 2) ? Wg : Wo;
        const float4* src4 = (const float4*)(wsrc + (size_t)unit * KDIM);
        #pragma unroll 2
        for (int m = 0; m < 12; ++m)
            W4[r * S4 + c0 + 16 * m] = src4[c0 + 16 * m];
        if (tid < 32) {
            const int g2 = tid >> 3;
            const float* bsrc = (g2 == 0) ? bfp : (g2 == 1) ? bip : (g2 == 2) ? bgp : bop;
            bias_s[tid] = bsrc[k0 + (tid & 7)];
        }
    }

    float* const hx_sec = out + (size_t)T_STEPS * BATCH * HID;  // buf0 (ends as hx)
    float* const cx_sec = hx_sec + BATCH * HID;                 // buf1 (ends as cx)

    const int lb2 = tid >> 3;   // cell-update mapping (tid<128)
    const int u2  = tid & 7;

    // zero h0 slab via bypass stores; publish flag=1. __syncthreads drains
    // vmcnt(0) before s_barrier -> h stores visible before the flag store.
    if (tid < 128)
        store_bypass(&hx_sec[(size_t)(bg0 + lb2) * HID + (k0 + u2)], 0.0f);
    __syncthreads();
    if (tid == 0)
        store_flag(&flags[kslice], 1u);

    // GEMM mapping: KQ=64 (full wave), 8x8 tile per thread.
    // wave w: batches (w&1)*8.. +7, rows (w>>1)*8.. +7.
    const int kq  = tid & 63;          // lane = K stripe
    const int wid = tid >> 6;          // wave 0..7
    const int bg8 = (wid & 1) * 8;     // batch offset in bgroup
    const int rw  = (wid >> 1) * 8;    // row offset (0,8,16,24)

    float c_reg = 0.0f;

    for (int t = 0; t < T_STEPS; ++t) {
        const float* h_read  = (t & 1) ? cx_sec : hx_sec;   // h_t in buf[t&1]
        float*       h_write = (t & 1) ? hx_sec : cx_sec;   // h_{t+1} -> buf[(t+1)&1]

        // ---- A: stage x_t (flag-independent; hides behind the poll) ----
        {
            const float4* xs = (const float4*)(x + ((size_t)t * BATCH + bg0) * DIN);
            #pragma unroll
            for (int m = 0; m < 2; ++m) {
                const int i4 = tid + 512 * m;               // 16b x 64 f4
                C4[(i4 >> 6) * S4 + (i4 & 63)] = xs[i4];
            }
        }
        __syncthreads();   // x staged; safe: previous D/E reads fenced above

        float acc[8][8];
        #pragma unroll
        for (int i = 0; i < 8; ++i)
            #pragma unroll
            for (int j = 0; j < 8; ++j) acc[i][j] = 0.0f;

        // one K-stripe slice: cv[8] resident; wv in pairs + sched_barrier
        // so peak live stays ~ acc(64)+cv(32)+wv(8)+addr < 128.
        auto gemm_kslice = [&](const int dq) {
            float4 cv[8];
            #pragma unroll
            for (int i = 0; i < 8; ++i) cv[i] = C4[(bg8 + i) * S4 + dq];
            #pragma unroll
            for (int jp = 0; jp < 4; ++jp) {
                const float4 w0 = W4[(rw + 2 * jp) * S4 + dq];
                const float4 w1 = W4[(rw + 2 * jp + 1) * S4 + dq];
                #pragma unroll
                for (int i = 0; i < 8; ++i) {
                    acc[i][2 * jp]     = fmaf(cv[i].x, w0.x, acc[i][2 * jp]);
                    acc[i][2 * jp]     = fmaf(cv[i].y, w0.y, acc[i][2 * jp]);
                    acc[i][2 * jp]     = fmaf(cv[i].z, w0.z, acc[i][2 * jp]);
                    acc[i][2 * jp]     = fmaf(cv[i].w, w0.w, acc[i][2 * jp]);
                    acc[i][2 * jp + 1] = fmaf(cv[i].x, w1.x, acc[i][2 * jp + 1]);
                    acc[i][2 * jp + 1] = fmaf(cv[i].y, w1.y, acc[i][2 * jp + 1]);
                    acc[i][2 * jp + 1] = fmaf(cv[i].z, w1.z, acc[i][2 * jp + 1]);
                    acc[i][2 * jp + 1] = fmaf(cv[i].w, w1.w, acc[i][2 * jp + 1]);
                }
                __builtin_amdgcn_sched_barrier(0);   // next wv pair stays below
            }
        };

        // ---- A2: x-part GEMM (K f4 0..63) — independent of h_t ----
        gemm_kslice(kq);

        // ---- B: wait until all 64 peers published h_t ----
        if (tid < 64) {
            const unsigned target = (unsigned)(t + 1);
            while (!__all((int)(load_flag(&flags[tid]) >= target)))
                __builtin_amdgcn_s_sleep(1);
        }
        __syncthreads();   // full barrier: gather can't hoist above

        // ---- C: gather h_t via bypass loads, full MLP (16 in flight) ----
        {
            const float* hsrc = h_read + (size_t)bg0 * HID;
            float hv[16];
            #pragma unroll
            for (int m = 0; m < 16; ++m)
                hv[m] = load_bypass(&hsrc[512 * m + tid]);
            float* Cf = (float*)C4;
            #pragma unroll
            for (int m = 0; m < 16; ++m)
                Cf[m * (S4 * 4) + 256 + tid] = hv[m];   // consecutive dwords: conflict-free
        }
        __syncthreads();

        // ---- D: h-part GEMM (K f4 64..191), 2 K-stripe slices ----
        #pragma unroll 1
        for (int it = 1; it < 3; ++it)
            gemm_kslice(kq + 64 * it);

        // ---- E: reduce 64 K-stripes via DPP (pure VALU), pack f4 write ----
        // 6 stages -> lanes 48-63 hold the full 64-lane sum; lane 48 writes
        // 2 packed float4 (8 rows) per batch.
        {
            const bool writer = (kq == 48);
            #pragma unroll
            for (int i = 0; i < 8; ++i) {
                float g[8];
                #pragma unroll
                for (int j = 0; j < 8; ++j) {
                    float v = acc[i][j];
                    DPP_ADD(v, 0xB1);  DPP_ADD(v, 0x4E);
                    DPP_ADD(v, 0x124); DPP_ADD(v, 0x128);
                    DPP_ADD(v, 0x142); DPP_ADD(v, 0x143);
                    g[j] = v;
                }
                if (writer) {
                    gates4[(bg8 + i) * 9 + (rw >> 2)]     =
                        make_float4(g[0], g[1], g[2], g[3]);
                    gates4[(bg8 + i) * 9 + (rw >> 2) + 1] =
                        make_float4(g[4], g[5], g[6], g[7]);
                }
            }
        }
        __syncthreads();

        // ---- F: LSTM cell update (one thread per (b, hidden unit)) ----
        if (tid < 128) {
            const float* gf = (const float*)gates4;   // stride 36 floats/batch
            const float pf = gf[lb2 * 36 + u2]      + bias_s[u2];
            const float pi = gf[lb2 * 36 + 8 + u2]  + bias_s[8 + u2];
            const float pg = gf[lb2 * 36 + 16 + u2] + bias_s[16 + u2];
            const float po = gf[lb2 * 36 + 24 + u2] + bias_s[24 + u2];
            const float fg = fast_sigmoid(pf);
            const float ig = fast_sigmoid(pi);
            const float gg = fast_tanh(pg);
            const float og = fast_sigmoid(po);
            c_reg = fg * c_reg + ig * gg;
            const float h = og * fast_tanh(c_reg);
            const int b = bg0 + lb2;
            const int k = k0 + u2;
            store_bypass(&h_write[(size_t)b * HID + k], h);   // coherent-direct
            out[((size_t)t * BATCH + b) * HID + k] = h;       // cached, flushed at end
        }
        __syncthreads();   // drains vmcnt(0): h bypass stores globally visible

        // ---- G: publish h_{t+1}: one relaxed store, no RMW ----
        if (tid == 0)
            store_flag(&flags[kslice], (unsigned)(t + 2));
    }

    // Final: hx (h_512) already in hx_sec. Overwrite buf1 (h_511) with c only
    // after all peers finished step 511 (flag = 513 => done reading h_511).
    if (tid < 64) {
        const unsigned target = (unsigned)(T_STEPS + 1);
        while (!__all((int)(load_flag(&flags[tid]) >= target)))
            __builtin_amdgcn_s_sleep(1);
    }
    __syncthreads();
    if (tid < 128)
        cx_sec[(size_t)(bg0 + lb2) * HID + (k0 + u2)] = c_reg;
}

extern "C" void kernel_launch(void* const* d_in, const int* in_sizes, int n_in,
                              void* d_out, int out_size, void* d_ws, size_t ws_size,
                              hipStream_t stream) {
    (void)in_sizes; (void)n_in; (void)ws_size; (void)out_size;
    const float* x  = (const float*)d_in[0];
    const float* Wf = (const float*)d_in[1];
    const float* bf = (const float*)d_in[2];
    const float* Wi = (const float*)d_in[3];
    const float* bi = (const float*)d_in[4];
    const float* Wg = (const float*)d_in[5];
    const float* bg = (const float*)d_in[6];
    const float* Wo = (const float*)d_in[7];
    const float* bo = (const float*)d_in[8];
    float* out = (float*)d_out;
    unsigned* flags = (unsigned*)d_ws;

    // flags[4 bgroups][64 producers], 4B each; must start 0 (d_ws poisoned)
    hipMemsetAsync(d_ws, 0, 4 * NPROD * sizeof(unsigned), stream);

    void* args[] = {&x, &Wf, &bf, &Wi, &bi, &Wg, &bg, &Wo, &bo, &out, &flags};
    hipLaunchCooperativeKernel(reinterpret_cast<void*>(lstm_persistent),
                               dim3(NBLK), dim3(512), args, 0, stream);
}

// Round 10
// 2763.456 us; speedup vs baseline: 1.1829x; 1.1829x over previous
//
#include <hip/hip_runtime.h>

static constexpr int T_STEPS = 512;
static constexpr int BATCH   = 64;
static constexpr int DIN     = 256;
static constexpr int HID     = 512;
static constexpr int KDIM    = DIN + HID;   // 768
static constexpr int S4      = 193;         // LDS row stride in float4 (192 data + 1 pad)
static constexpr int NBLK    = 256;
static constexpr int NPROD   = 64;          // producers (kslices) per bgroup

__device__ __forceinline__ float fast_sigmoid(float v) {
    return 1.0f / (1.0f + __expf(-v));
}
__device__ __forceinline__ float fast_tanh(float v) {
    return 1.0f - 2.0f / (__expf(2.0f * v) + 1.0f);
}

// Relaxed agent-scope ops: L1+L2 bypass, served at the device coherence
// point. No buffer_wbl2 / buffer_inv anywhere (rounds 1-3 lesson: per-WG
// full-L2 writeback+invalidate is catastrophic).
__device__ __forceinline__ void store_bypass(float* p, float v) {
    __hip_atomic_store((unsigned int*)p, __float_as_uint(v),
                       __ATOMIC_RELAXED, __HIP_MEMORY_SCOPE_AGENT);
}
__device__ __forceinline__ float load_bypass(const float* p) {
    return __uint_as_float(__hip_atomic_load((const unsigned int*)p,
                           __ATOMIC_RELAXED, __HIP_MEMORY_SCOPE_AGENT));
}
__device__ __forceinline__ void store_flag(unsigned* p, unsigned v) {
    __hip_atomic_store(p, v, __ATOMIC_RELAXED, __HIP_MEMORY_SCOPE_AGENT);
}
__device__ __forceinline__ unsigned load_flag(const unsigned* p) {
    return __hip_atomic_load(p, __ATOMIC_RELAXED, __HIP_MEMORY_SCOPE_AGENT);
}

// DPP-rotate add: v += lane_permuted(v). All-VALU (no LDS pipe). ctrl is a
// literal: 0xB1 quad_perm xor1, 0x4E quad_perm xor2, 0x124 row_ror:4,
// 0x128 row_ror:8 -> every lane holds its 16-lane row sum. 0x142
// row_bcast15: lanes 16-31 += lane15 (sum 0..15) -> lanes 16-31 hold
// sum(0..31); lanes 48-63 += lane47 -> sum(32..63). bound_ctrl=1.
#define DPP_ADD(v, ctrl)                                                  \
    (v) += __uint_as_float(__builtin_amdgcn_update_dpp(                   \
        0u, __float_as_uint(v), (ctrl), 0xF, 0xF, true))

// ROUND 7:  per-producer flags + wave-wide __all poll; x-GEMM above wait.
// ROUND 8-11 (dead end): W-in-registers spills (128-VGPR allocator pin).
// ROUND 12: E-reduce ds_swizzle -> VALU DPP: 3555 -> 2766us.
// ROUND 13: retile 4x4/KQ16 -> 8x4/KQ32: conflicts 2.08e8 -> 2.1e6;
//           dur -4%. LDS READ COUNT is the binding resource, not conflicts.
// ROUND 14 (dead end): 8x8/KQ64 retile regressed 23%: VGPR_Count=88 with a
//           64-f32 acc => compiler shuttled acc through AGPRs (no memory
//           spill, but VALU moves per FMA) + sched_barrier serialization.
//           LESSON: acc+transients budget ~90 regs; KQ=64 forces 8x8 acc;
//           8x4/KQ32 (R8) is the retile optimum. Family exhausted.
// ROUND 15: attack the ~1.5us/step serial residue on the R8 base:
//           (1) x-staging moved into the F-shadow (tid>=128 idle there);
//               removes phase A + one barrier from the loop top.
//           (2) wv of h-slices 2,3 prefetched into regs BEFORE the flag
//               wait (W4 static => legal): 8 of 24 critical wv reads move
//               into the wait slack. Peak live ~110 < 128.
//           (3) loop-invariant LDS bases hoisted; slice reads become
//               base + compile-time immediate (16-bit ds offset field).
//           No sched_barrier anywhere (R14 lesson).
__global__ __launch_bounds__(512, 1)
void lstm_persistent(const float* __restrict__ x,
                     const float* __restrict__ Wf, const float* __restrict__ bfp,
                     const float* __restrict__ Wi, const float* __restrict__ bip,
                     const float* __restrict__ Wg, const float* __restrict__ bgp,
                     const float* __restrict__ Wo, const float* __restrict__ bop,
                     float* __restrict__ out, unsigned* __restrict__ flag_ws) {
    __shared__ float4 W4[32 * S4];        // 32 rows x 768 fp32
    __shared__ float4 C4[16 * S4];        // combined [x|h] for 16 b
    __shared__ float4 gates4[16 * 9];     // gates [16 b][36 f stride]
    __shared__ float  bias_s[32];

    const int tid = threadIdx.x;
    const int wg  = blockIdx.x;
    const int bgroup = (wg & 7) >> 1;                  // 0..3
    const int kslice = ((wg >> 3) << 1) | (wg & 1);    // 0..63
    const int bg0 = bgroup * 16;
    const int k0  = kslice * 8;

    // 64 flags per bgroup, packed 256 B (one wave-instruction covers all 64)
    unsigned* const flags = flag_ws + bgroup * NPROD;

    // ---- one-time: stage 32 weight rows (gate*8 + unit) into LDS ----
    {
        const int r    = tid >> 4;     // 0..31
        const int c0   = tid & 15;
        const int gate = r >> 3;
        const int unit = k0 + (r & 7);
        const float* wsrc = (gate == 0) ? Wf : (gate == 1) ? Wi : (gate == 2) ? Wg : Wo;
        const float4* src4 = (const float4*)(wsrc + (size_t)unit * KDIM);
        #pragma unroll 2
        for (int m = 0; m < 12; ++m)
            W4[r * S4 + c0 + 16 * m] = src4[c0 + 16 * m];
        if (tid < 32) {
            const int g2 = tid >> 3;
            const float* bsrc = (g2 == 0) ? bfp : (g2 == 1) ? bip : (g2 == 2) ? bgp : bop;
            bias_s[tid] = bsrc[k0 + (tid & 7)];
        }
    }

    // ---- one-time: stage x_0 (in-loop staging happens in the F-shadow) ----
    {
        const float4* xs = (const float4*)(x + (size_t)bg0 * DIN);
        #pragma unroll
        for (int m = 0; m < 2; ++m) {
            const int i4 = tid + 512 * m;               // 16b x 64 f4
            C4[(i4 >> 6) * S4 + (i4 & 63)] = xs[i4];
        }
    }

    float* const hx_sec = out + (size_t)T_STEPS * BATCH * HID;  // buf0 (ends as hx)
    float* const cx_sec = hx_sec + BATCH * HID;                 // buf1 (ends as cx)

    const int lb2 = tid >> 3;   // cell-update mapping (tid<128)
    const int u2  = tid & 7;

    // zero h0 slab via bypass stores; publish flag=1. __syncthreads drains
    // vmcnt(0) before s_barrier -> h stores visible before the flag store.
    // (barrier also covers W4 / x_0 staging visibility.)
    if (tid < 128)
        store_bypass(&hx_sec[(size_t)(bg0 + lb2) * HID + (k0 + u2)], 0.0f);
    __syncthreads();
    if (tid == 0)
        store_flag(&flags[kslice], 1u);

    // GEMM mapping: 32 K-stripes per reduction, 8x4 tile per thread.
    const int kq  = tid & 31;        // 0..31 -> K stripe
    const int rg  = (tid >> 5) & 7;  // 0..7  -> rows rg*4..+3
    const int lbg = tid >> 8;        // 0..1  -> batches lbg*8..+7

    // Loop-invariant LDS bases: every slice read below is base +
    // compile-time offset (i*S4 + 32*it f4), within the 16-bit ds field.
    const float4* const C4r = &C4[(lbg * 8) * S4 + kq];
    const float4* const W4r = &W4[(rg * 4) * S4 + kq];

    float c_reg = 0.0f;

    for (int t = 0; t < T_STEPS; ++t) {
        const float* h_read  = (t & 1) ? cx_sec : hx_sec;   // h_t in buf[t&1]
        float*       h_write = (t & 1) ? hx_sec : cx_sec;   // h_{t+1} -> buf[(t+1)&1]

        // ---- A2: x-part GEMM (slices 0,1) — x_t staged last F-shadow ----
        float acc[8][4];
        #pragma unroll
        for (int i = 0; i < 8; ++i)
            #pragma unroll
            for (int j = 0; j < 4; ++j) acc[i][j] = 0.0f;

        #pragma unroll 1
        for (int it = 0; it < 2; ++it) {
            float4 cv[8], wv[4];
            #pragma unroll
            for (int i = 0; i < 8; ++i) cv[i] = C4r[i * S4 + 32 * it];
            #pragma unroll
            for (int j = 0; j < 4; ++j) wv[j] = W4r[j * S4 + 32 * it];
            #pragma unroll
            for (int i = 0; i < 8; ++i) {
                #pragma unroll
                for (int j = 0; j < 4; ++j) {
                    acc[i][j] = fmaf(cv[i].x, wv[j].x, acc[i][j]);
                    acc[i][j] = fmaf(cv[i].y, wv[j].y, acc[i][j]);
                    acc[i][j] = fmaf(cv[i].z, wv[j].z, acc[i][j]);
                    acc[i][j] = fmaf(cv[i].w, wv[j].w, acc[i][j]);
                }
            }
        }

        // ---- wv prefetch for h-slices 2,3 (W4 static: legal pre-wait) ----
        float4 wp2[4], wp3[4];
        #pragma unroll
        for (int j = 0; j < 4; ++j) {
            wp2[j] = W4r[j * S4 + 64];
            wp3[j] = W4r[j * S4 + 96];
        }

        // ---- B: wait until all 64 peers published h_t ----
        if (tid < 64) {
            const unsigned target = (unsigned)(t + 1);
            while (!__all((int)(load_flag(&flags[tid]) >= target)))
                __builtin_amdgcn_s_sleep(1);
        }
        __syncthreads();   // full barrier: gather can't hoist above

        // ---- C: gather h_t via bypass loads, full MLP (16 in flight) ----
        {
            const float* hsrc = h_read + (size_t)bg0 * HID;
            float hv[16];
            #pragma unroll
            for (int m = 0; m < 16; ++m)
                hv[m] = load_bypass(&hsrc[512 * m + tid]);
            float* Cf = (float*)C4;
            #pragma unroll
            for (int m = 0; m < 16; ++m)
                Cf[m * (S4 * 4) + 256 + tid] = hv[m];   // consecutive dwords: conflict-free
        }
        __syncthreads();

        // ---- D: h-part GEMM. Slices 2,3 use prefetched wv (cv-only LDS);
        //      slices 4,5 read wv from LDS as before. ----
        #pragma unroll 1
        for (int it = 2; it < 4; ++it) {
            const float4* wp = (it == 2) ? wp2 : wp3;
            float4 cv[8];
            #pragma unroll
            for (int i = 0; i < 8; ++i) cv[i] = C4r[i * S4 + 32 * it];
            #pragma unroll
            for (int i = 0; i < 8; ++i) {
                #pragma unroll
                for (int j = 0; j < 4; ++j) {
                    acc[i][j] = fmaf(cv[i].x, wp[j].x, acc[i][j]);
                    acc[i][j] = fmaf(cv[i].y, wp[j].y, acc[i][j]);
                    acc[i][j] = fmaf(cv[i].z, wp[j].z, acc[i][j]);
                    acc[i][j] = fmaf(cv[i].w, wp[j].w, acc[i][j]);
                }
            }
        }
        #pragma unroll 1
        for (int it = 4; it < 6; ++it) {
            float4 cv[8], wv[4];
            #pragma unroll
            for (int i = 0; i < 8; ++i) cv[i] = C4r[i * S4 + 32 * it];
            #pragma unroll
            for (int j = 0; j < 4; ++j) wv[j] = W4r[j * S4 + 32 * it];
            #pragma unroll
            for (int i = 0; i < 8; ++i) {
                #pragma unroll
                for (int j = 0; j < 4; ++j) {
                    acc[i][j] = fmaf(cv[i].x, wv[j].x, acc[i][j]);
                    acc[i][j] = fmaf(cv[i].y, wv[j].y, acc[i][j]);
                    acc[i][j] = fmaf(cv[i].z, wv[j].z, acc[i][j]);
                    acc[i][j] = fmaf(cv[i].w, wv[j].w, acc[i][j]);
                }
            }
        }

        // ---- E: reduce 32 K-stripes via DPP (pure VALU), pack f4 write ----
        {
            const bool writer = ((tid & 31) == 16);
            #pragma unroll
            for (int i = 0; i < 8; ++i) {
                float g0, g1, g2, g3;
                {
                    float v = acc[i][0];
                    DPP_ADD(v, 0xB1); DPP_ADD(v, 0x4E);
                    DPP_ADD(v, 0x124); DPP_ADD(v, 0x128);
                    DPP_ADD(v, 0x142); g0 = v;
                }
                {
                    float v = acc[i][1];
                    DPP_ADD(v, 0xB1); DPP_ADD(v, 0x4E);
                    DPP_ADD(v, 0x124); DPP_ADD(v, 0x128);
                    DPP_ADD(v, 0x142); g1 = v;
                }
                {
                    float v = acc[i][2];
                    DPP_ADD(v, 0xB1); DPP_ADD(v, 0x4E);
                    DPP_ADD(v, 0x124); DPP_ADD(v, 0x128);
                    DPP_ADD(v, 0x142); g2 = v;
                }
                {
                    float v = acc[i][3];
                    DPP_ADD(v, 0xB1); DPP_ADD(v, 0x4E);
                    DPP_ADD(v, 0x124); DPP_ADD(v, 0x128);
                    DPP_ADD(v, 0x142); g3 = v;
                }
                if (writer)
                    gates4[(lbg * 8 + i) * 9 + rg] = make_float4(g0, g1, g2, g3);
            }
        }
        __syncthreads();

        // ---- F: LSTM cell update; meanwhile ALL threads stage x_{t+1}
        //      into the C4 x-region (D reads of x_t are fenced above). ----
        {
            const int tn = (t + 1 < T_STEPS) ? (t + 1) : t;   // clamp: last iter harmless
            const float4* xs = (const float4*)(x + ((size_t)tn * BATCH + bg0) * DIN);
            #pragma unroll
            for (int m = 0; m < 2; ++m) {
                const int i4 = tid + 512 * m;               // 16b x 64 f4
                C4[(i4 >> 6) * S4 + (i4 & 63)] = xs[i4];
            }
        }
        if (tid < 128) {
            const float* gf = (const float*)gates4;   // stride 36 floats/batch
            const float pf = gf[lb2 * 36 + u2]      + bias_s[u2];
            const float pi = gf[lb2 * 36 + 8 + u2]  + bias_s[8 + u2];
            const float pg = gf[lb2 * 36 + 16 + u2] + bias_s[16 + u2];
            const float po = gf[lb2 * 36 + 24 + u2] + bias_s[24 + u2];
            const float fg = fast_sigmoid(pf);
            const float ig = fast_sigmoid(pi);
            const float gg = fast_tanh(pg);
            const float og = fast_sigmoid(po);
            c_reg = fg * c_reg + ig * gg;
            const float h = og * fast_tanh(c_reg);
            const int b = bg0 + lb2;
            const int k = k0 + u2;
            store_bypass(&h_write[(size_t)b * HID + k], h);   // coherent-direct
            out[((size_t)t * BATCH + b) * HID + k] = h;       // cached, flushed at end
        }
        __syncthreads();   // drains vmcnt(0): h stores visible; x_{t+1} staged

        // ---- G: publish h_{t+1}: one relaxed store, no RMW ----
        if (tid == 0)
            store_flag(&flags[kslice], (unsigned)(t + 2));
    }

    // Final: hx (h_512) already in hx_sec. Overwrite buf1 (h_511) with c only
    // after all peers finished step 511 (flag = 513 => done reading h_511).
    if (tid < 64) {
        const unsigned target = (unsigned)(T_STEPS + 1);
        while (!__all((int)(load_flag(&flags[tid]) >= target)))
            __builtin_amdgcn_s_sleep(1);
    }
    __syncthreads();
    if (tid < 128)
        cx_sec[(size_t)(bg0 + lb2) * HID + (k0 + u2)] = c_reg;
}

extern "C" void kernel_launch(void* const* d_in, const int* in_sizes, int n_in,
                              void* d_out, int out_size, void* d_ws, size_t ws_size,
                              hipStream_t stream) {
    (void)in_sizes; (void)n_in; (void)ws_size; (void)out_size;
    const float* x  = (const float*)d_in[0];
    const float* Wf = (const float*)d_in[1];
    const float* bf = (const float*)d_in[2];
    const float* Wi = (const float*)d_in[3];
    const float* bi = (const float*)d_in[4];
    const float* Wg = (const float*)d_in[5];
    const float* bg = (const float*)d_in[6];
    const float* Wo = (const float*)d_in[7];
    const float* bo = (const float*)d_in[8];
    float* out = (float*)d_out;
    unsigned* flags = (unsigned*)d_ws;

    // flags[4 bgroups][64 producers], 4B each; must start 0 (d_ws poisoned)
    hipMemsetAsync(d_ws, 0, 4 * NPROD * sizeof(unsigned), stream);

    void* args[] = {&x, &Wf, &bf, &Wi, &bi, &Wg, &bg, &Wo, &bo, &out, &flags};
    hipLaunchCooperativeKernel(reinterpret_cast<void*>(lstm_persistent),
                               dim3(NBLK), dim3(512), args, 0, stream);
}

// Round 11
// 2696.019 us; speedup vs baseline: 1.2125x; 1.0250x over previous
//
#include <hip/hip_runtime.h>

static constexpr int T_STEPS = 512;
static constexpr int BATCH   = 64;
static constexpr int DIN     = 256;
static constexpr int HID     = 512;
static constexpr int KDIM    = DIN + HID;   // 768
static constexpr int S4      = 193;         // LDS row stride in float4 (192 data + 1 pad)
static constexpr int NBLK    = 256;
static constexpr int NPROD   = 64;          // producers (kslices) per bgroup

__device__ __forceinline__ float fast_sigmoid(float v) {
    return 1.0f / (1.0f + __expf(-v));
}
__device__ __forceinline__ float fast_tanh(float v) {
    return 1.0f - 2.0f / (__expf(2.0f * v) + 1.0f);
}

// Relaxed agent-scope ops: L1+L2 bypass, served at the device coherence
// point. No buffer_wbl2 / buffer_inv anywhere (rounds 1-3 lesson: per-WG
// full-L2 writeback+invalidate is catastrophic).
__device__ __forceinline__ void store_bypass(float* p, float v) {
    __hip_atomic_store((unsigned int*)p, __float_as_uint(v),
                       __ATOMIC_RELAXED, __HIP_MEMORY_SCOPE_AGENT);
}
__device__ __forceinline__ float load_bypass(const float* p) {
    return __uint_as_float(__hip_atomic_load((const unsigned int*)p,
                           __ATOMIC_RELAXED, __HIP_MEMORY_SCOPE_AGENT));
}
__device__ __forceinline__ void store_flag(unsigned* p, unsigned v) {
    __hip_atomic_store(p, v, __ATOMIC_RELAXED, __HIP_MEMORY_SCOPE_AGENT);
}
__device__ __forceinline__ unsigned load_flag(const unsigned* p) {
    return __hip_atomic_load(p, __ATOMIC_RELAXED, __HIP_MEMORY_SCOPE_AGENT);
}

// DPP-rotate add: v += lane_permuted(v). All-VALU (no LDS pipe). ctrl is a
// literal: 0xB1 quad_perm xor1, 0x4E quad_perm xor2, 0x124 row_ror:4,
// 0x128 row_ror:8 -> every lane holds its 16-lane row sum. 0x142
// row_bcast15: lanes 16-31 += lane15 (sum 0..15) -> lanes 16-31 hold
// sum(0..31); lanes 48-63 += lane47 -> sum(32..63). bound_ctrl=1.
#define DPP_ADD(v, ctrl)                                                  \
    (v) += __uint_as_float(__builtin_amdgcn_update_dpp(                   \
        0u, __float_as_uint(v), (ctrl), 0xF, 0xF, true))

// ROUND 7:  per-producer flags + wave-wide __all poll; x-GEMM above wait.
// ROUND 8-11 (dead end): W-in-registers spills (128-VGPR allocator pin).
// ROUND 12: E-reduce ds_swizzle -> VALU DPP: 3555 -> 2766us.
// ROUND 13: retile 4x4/KQ16 -> 8x4/KQ32: conflicts 2.08e8 -> 2.1e6;
//           dur -4%. LDS READ COUNT is the binding resource, not conflicts.
// ROUND 14 (dead end): 8x8/KQ64: AGPR-shuttled acc (VGPR=88 w/ 64-f32 acc)
//           + sched_barrier serialization = +23%. 8x4/KQ32 is the optimum.
// ROUND 15 (neutral): F-shadow x-staging + wv prefetch + hoisted bases;
//           dispatch durs within noise of R8. LESSON: the ~1.5us/step
//           residue is the inter-WG latency chain (store drain -> flag
//           propagate -> poll -> LLC gather); local-work shuffling can't
//           hide it (only A2's 0.4us fits under the wait).
// ROUND 16: fuse the cell update INTO the GEMM half-waves via UNIT-MAJOR
//           W rows (row r = unit*4 + gate, was gate*8 + unit). Half-wave
//           (lbg,rg) now computes all 4 gates of unit rg for its 8
//           batches; after the verified DPP ladder, lanes 16-23 hold each
//           batch's (g0..g3) in-register -> cell update in-wave. Removes:
//           gates LDS array, one __syncthreads, F's LDS reads, and the
//           2-wave F serialization (16 half-waves update in parallel).
//           Bias hoisted to 4 registers outside the t-loop.
__global__ __launch_bounds__(512, 1)
void lstm_persistent(const float* __restrict__ x,
                     const float* __restrict__ Wf, const float* __restrict__ bfp,
                     const float* __restrict__ Wi, const float* __restrict__ bip,
                     const float* __restrict__ Wg, const float* __restrict__ bgp,
                     const float* __restrict__ Wo, const float* __restrict__ bop,
                     float* __restrict__ out, unsigned* __restrict__ flag_ws) {
    __shared__ float4 W4[32 * S4];        // 32 rows x 768 fp32 (UNIT-MAJOR rows)
    __shared__ float4 C4[16 * S4];        // combined [x|h] for 16 b
    __shared__ float  bias_s[32];         // unit-major: bias_s[u*4+g]

    const int tid = threadIdx.x;
    const int wg  = blockIdx.x;
    const int bgroup = (wg & 7) >> 1;                  // 0..3
    const int kslice = ((wg >> 3) << 1) | (wg & 1);    // 0..63
    const int bg0 = bgroup * 16;
    const int k0  = kslice * 8;

    // 64 flags per bgroup, packed 256 B (one wave-instruction covers all 64)
    unsigned* const flags = flag_ws + bgroup * NPROD;

    // ---- one-time: stage 32 weight rows UNIT-MAJOR (r = unit*4+gate) ----
    {
        const int r    = tid >> 4;     // 0..31
        const int c0   = tid & 15;
        const int gate = r & 3;
        const int unit = k0 + (r >> 2);
        const float* wsrc = (gate == 0) ? Wf : (gate == 1) ? Wi : (gate == 2) ? Wg : Wo;
        const float4* src4 = (const float4*)(wsrc + (size_t)unit * KDIM);
        #pragma unroll 2
        for (int m = 0; m < 12; ++m)
            W4[r * S4 + c0 + 16 * m] = src4[c0 + 16 * m];
        if (tid < 32) {
            const int g2 = tid & 3;
            const float* bsrc = (g2 == 0) ? bfp : (g2 == 1) ? bip : (g2 == 2) ? bgp : bop;
            bias_s[tid] = bsrc[k0 + (tid >> 2)];
        }
    }

    // ---- one-time: stage x_0 (in-loop staging happens post-D) ----
    {
        const float4* xs = (const float4*)(x + (size_t)bg0 * DIN);
        #pragma unroll
        for (int m = 0; m < 2; ++m) {
            const int i4 = tid + 512 * m;               // 16b x 64 f4
            C4[(i4 >> 6) * S4 + (i4 & 63)] = xs[i4];
        }
    }

    float* const hx_sec = out + (size_t)T_STEPS * BATCH * HID;  // buf0 (ends as hx)
    float* const cx_sec = hx_sec + BATCH * HID;                 // buf1 (ends as cx)

    // zero h0 slab via bypass stores; publish flag=1. __syncthreads drains
    // vmcnt(0) before s_barrier -> h stores visible before the flag store.
    // (barrier also covers W4 / bias / x_0 staging visibility.)
    if (tid < 128)
        store_bypass(&hx_sec[(size_t)(bg0 + (tid >> 3)) * HID + (k0 + (tid & 7))], 0.0f);
    __syncthreads();
    if (tid == 0)
        store_flag(&flags[kslice], 1u);

    // GEMM mapping: 32 K-stripes per reduction, 8x4 tile per half-wave.
    const int kq  = tid & 31;        // 0..31 -> K stripe (= lane in half-wave)
    const int rg  = (tid >> 5) & 7;  // 0..7  -> UNIT rg (4 gate rows)
    const int lbg = tid >> 8;        // 0..1  -> batches lbg*8..+7

    // Loop-invariant LDS bases: every slice read below is base +
    // compile-time offset (i*S4 + 32*it f4), within the 16-bit ds field.
    const float4* const C4r = &C4[(lbg * 8) * S4 + kq];
    const float4* const W4r = &W4[(rg * 4) * S4 + kq];

    // Owner lanes: sub 16..23 own batch (sub-16); they hold c and write h.
    const int  sub   = tid & 31;
    const bool owner = (sub >= 16) && (sub < 24);
    const int  ob    = bg0 + lbg * 8 + (sub - 16);   // owner's batch
    const int  ok    = k0 + rg;                      // owner's hidden unit

    // bias for unit rg, gates 0..3 — static, hoist to registers.
    const float bb0 = bias_s[rg * 4 + 0];
    const float bb1 = bias_s[rg * 4 + 1];
    const float bb2 = bias_s[rg * 4 + 2];
    const float bb3 = bias_s[rg * 4 + 3];

    float c_reg = 0.0f;

    for (int t = 0; t < T_STEPS; ++t) {
        const float* h_read  = (t & 1) ? cx_sec : hx_sec;   // h_t in buf[t&1]
        float*       h_write = (t & 1) ? hx_sec : cx_sec;   // h_{t+1} -> buf[(t+1)&1]

        // ---- A2: x-part GEMM (slices 0,1) — x_t staged last step ----
        float acc[8][4];
        #pragma unroll
        for (int i = 0; i < 8; ++i)
            #pragma unroll
            for (int j = 0; j < 4; ++j) acc[i][j] = 0.0f;

        #pragma unroll 1
        for (int it = 0; it < 2; ++it) {
            float4 cv[8], wv[4];
            #pragma unroll
            for (int i = 0; i < 8; ++i) cv[i] = C4r[i * S4 + 32 * it];
            #pragma unroll
            for (int j = 0; j < 4; ++j) wv[j] = W4r[j * S4 + 32 * it];
            #pragma unroll
            for (int i = 0; i < 8; ++i) {
                #pragma unroll
                for (int j = 0; j < 4; ++j) {
                    acc[i][j] = fmaf(cv[i].x, wv[j].x, acc[i][j]);
                    acc[i][j] = fmaf(cv[i].y, wv[j].y, acc[i][j]);
                    acc[i][j] = fmaf(cv[i].z, wv[j].z, acc[i][j]);
                    acc[i][j] = fmaf(cv[i].w, wv[j].w, acc[i][j]);
                }
            }
        }

        // ---- B: wait until all 64 peers published h_t ----
        if (tid < 64) {
            const unsigned target = (unsigned)(t + 1);
            while (!__all((int)(load_flag(&flags[tid]) >= target)))
                __builtin_amdgcn_s_sleep(1);
        }
        __syncthreads();   // full barrier: gather can't hoist above

        // ---- C: gather h_t via bypass loads, full MLP (16 in flight) ----
        {
            const float* hsrc = h_read + (size_t)bg0 * HID;
            float hv[16];
            #pragma unroll
            for (int m = 0; m < 16; ++m)
                hv[m] = load_bypass(&hsrc[512 * m + tid]);
            float* Cf = (float*)C4;
            #pragma unroll
            for (int m = 0; m < 16; ++m)
                Cf[m * (S4 * 4) + 256 + tid] = hv[m];   // consecutive dwords: conflict-free
        }
        __syncthreads();

        // ---- D: h-part GEMM (slices 2..5) ----
        #pragma unroll 1
        for (int it = 2; it < 6; ++it) {
            float4 cv[8], wv[4];
            #pragma unroll
            for (int i = 0; i < 8; ++i) cv[i] = C4r[i * S4 + 32 * it];
            #pragma unroll
            for (int j = 0; j < 4; ++j) wv[j] = W4r[j * S4 + 32 * it];
            #pragma unroll
            for (int i = 0; i < 8; ++i) {
                #pragma unroll
                for (int j = 0; j < 4; ++j) {
                    acc[i][j] = fmaf(cv[i].x, wv[j].x, acc[i][j]);
                    acc[i][j] = fmaf(cv[i].y, wv[j].y, acc[i][j]);
                    acc[i][j] = fmaf(cv[i].z, wv[j].z, acc[i][j]);
                    acc[i][j] = fmaf(cv[i].w, wv[j].w, acc[i][j]);
                }
            }
        }

        // ---- stage x_{t+1} into the C4 x-region. Legal here: all waves
        //      passed the post-C barrier; x_t reads (A2) were pre-B; D/E
        //      touch only the h-region/registers. Global-load latency
        //      hides under E's DPP chain. ----
        {
            const int tn = (t + 1 < T_STEPS) ? (t + 1) : t;   // clamp: last iter harmless
            const float4* xs = (const float4*)(x + ((size_t)tn * BATCH + bg0) * DIN);
            #pragma unroll
            for (int m = 0; m < 2; ++m) {
                const int i4 = tid + 512 * m;               // 16b x 64 f4
                C4[(i4 >> 6) * S4 + (i4 & 63)] = xs[i4];
            }
        }

        // ---- E (fused): DPP-reduce 32 stripes; lane 16+i captures batch
        //      i's 4 gate pre-acts in-register (unit-major W => this
        //      half-wave owns all 4 gates of unit rg). ----
        float pf = 0.0f, pi = 0.0f, pg = 0.0f, po = 0.0f;
        #pragma unroll
        for (int i = 0; i < 8; ++i) {
            float g0, g1, g2, g3;
            {
                float v = acc[i][0];
                DPP_ADD(v, 0xB1); DPP_ADD(v, 0x4E);
                DPP_ADD(v, 0x124); DPP_ADD(v, 0x128);
                DPP_ADD(v, 0x142); g0 = v;
            }
            {
                float v = acc[i][1];
                DPP_ADD(v, 0xB1); DPP_ADD(v, 0x4E);
                DPP_ADD(v, 0x124); DPP_ADD(v, 0x128);
                DPP_ADD(v, 0x142); g1 = v;
            }
            {
                float v = acc[i][2];
                DPP_ADD(v, 0xB1); DPP_ADD(v, 0x4E);
                DPP_ADD(v, 0x124); DPP_ADD(v, 0x128);
                DPP_ADD(v, 0x142); g2 = v;
            }
            {
                float v = acc[i][3];
                DPP_ADD(v, 0xB1); DPP_ADD(v, 0x4E);
                DPP_ADD(v, 0x124); DPP_ADD(v, 0x128);
                DPP_ADD(v, 0x142); g3 = v;
            }
            if (sub == 16 + i) { pf = g0; pi = g1; pg = g2; po = g3; }
        }

        // ---- F (in-wave): owner lanes update cell state, store h ----
        if (owner) {
            const float fg = fast_sigmoid(pf + bb0);
            const float ig = fast_sigmoid(pi + bb1);
            const float gg = fast_tanh(pg + bb2);
            const float og = fast_sigmoid(po + bb3);
            c_reg = fg * c_reg + ig * gg;
            const float h = og * fast_tanh(c_reg);
            store_bypass(&h_write[(size_t)ob * HID + ok], h);   // coherent-direct
            out[((size_t)t * BATCH + ob) * HID + ok] = h;       // cached, flushed at end
        }
        __syncthreads();   // drains vmcnt(0): h stores visible; x_{t+1} staged

        // ---- G: publish h_{t+1}: one relaxed store, no RMW ----
        if (tid == 0)
            store_flag(&flags[kslice], (unsigned)(t + 2));
    }

    // Final: hx (h_512) already in hx_sec. Overwrite buf1 (h_511) with c only
    // after all peers finished step 511 (flag = 513 => done reading h_511).
    if (tid < 64) {
        const unsigned target = (unsigned)(T_STEPS + 1);
        while (!__all((int)(load_flag(&flags[tid]) >= target)))
            __builtin_amdgcn_s_sleep(1);
    }
    __syncthreads();
    if (owner)
        cx_sec[(size_t)ob * HID + ok] = c_reg;
}

extern "C" void kernel_launch(void* const* d_in, const int* in_sizes, int n_in,
                              void* d_out, int out_size, void* d_ws, size_t ws_size,
                              hipStream_t stream) {
    (void)in_sizes; (void)n_in; (void)ws_size; (void)out_size;
    const float* x  = (const float*)d_in[0];
    const float* Wf = (const float*)d_in[1];
    const float* bf = (const float*)d_in[2];
    const float* Wi = (const float*)d_in[3];
    const float* bi = (const float*)d_in[4];
    const float* Wg = (const float*)d_in[5];
    const float* bg = (const float*)d_in[6];
    const float* Wo = (const float*)d_in[7];
    const float* bo = (const float*)d_in[8];
    float* out = (float*)d_out;
    unsigned* flags = (unsigned*)d_ws;

    // flags[4 bgroups][64 producers], 4B each; must start 0 (d_ws poisoned)
    hipMemsetAsync(d_ws, 0, 4 * NPROD * sizeof(unsigned), stream);

    void* args[] = {&x, &Wf, &bf, &Wi, &bi, &Wg, &bg, &Wo, &bo, &out, &flags};
    hipLaunchCooperativeKernel(reinterpret_cast<void*>(lstm_persistent),
                               dim3(NBLK), dim3(512), args, 0, stream);
}